// Round 1
// baseline (385.101 us; speedup 1.0000x reference)
//
#include <hip/hip_runtime.h>
#include <hip/hip_bf16.h>

// Problem constants
#define NROWS 8192
#define INF   4096
#define OUTF  4096
#define G     1024          // INF / 4

typedef _Float16 f16x8 __attribute__((ext_vector_type(8)));
typedef float    f32x4 __attribute__((ext_vector_type(4)));

// ---------------- Kernel 1: global absmax over input ----------------
__global__ void absmax_kernel(const float4* __restrict__ x, int n4,
                              unsigned int* __restrict__ out_bits) {
    float m = 0.f;
    for (int i = blockIdx.x * blockDim.x + threadIdx.x; i < n4;
         i += gridDim.x * blockDim.x) {
        float4 v = x[i];
        m = fmaxf(m, fmaxf(fmaxf(fabsf(v.x), fabsf(v.y)),
                           fmaxf(fabsf(v.z), fabsf(v.w))));
    }
    // wave (64-lane) reduction
    for (int off = 32; off; off >>= 1)
        m = fmaxf(m, __shfl_down(m, off));
    __shared__ float wm[4];
    int lane = threadIdx.x & 63, wave = threadIdx.x >> 6;
    if (lane == 0) wm[wave] = m;
    __syncthreads();
    if (threadIdx.x == 0) {
        float bm = fmaxf(fmaxf(wm[0], wm[1]), fmaxf(wm[2], wm[3]));
        atomicMax(out_bits, __float_as_uint(bm));  // nonneg floats: uint order == float order
    }
}

// ------- Kernel 2: quantize + group-of-4 sum -> fp16 x_sum [N][G] -------
__global__ void quant_kernel(const float4* __restrict__ x,
                             _Float16* __restrict__ xs,
                             const unsigned int* __restrict__ max_bits,
                             int ngroups) {
    int i = blockIdx.x * blockDim.x + threadIdx.x;
    if (i >= ngroups) return;
    float s = __uint_as_float(*max_bits) * (1.0f / 127.0f);  // act_scale
    float4 v = x[i];
    float q0 = fminf(fmaxf(rintf(v.x / s), -128.f), 127.f);
    float q1 = fminf(fmaxf(rintf(v.y / s), -128.f), 127.f);
    float q2 = fminf(fmaxf(rintf(v.z / s), -128.f), 127.f);
    float q3 = fminf(fmaxf(rintf(v.w / s), -128.f), 127.f);
    xs[i] = (_Float16)(q0 + q1 + q2 + q3);   // integer in [-512,508]: exact in fp16
}

// ------- Kernel 3: weight group-of-4 sum -> fp16 w_sum [OUT][G] -------
__global__ void wsum_kernel(const float4* __restrict__ w,
                            _Float16* __restrict__ ws,
                            int ngroups) {
    int i = blockIdx.x * blockDim.x + threadIdx.x;
    if (i >= ngroups) return;
    float4 v = w[i];
    ws[i] = (_Float16)(v.x + v.y + v.z + v.w);  // integer in [-4,4]: exact
}

// ---------------- Kernel 4: f16 MFMA GEMM (m97 structure) ----------------
// C[m][n] = sum_k A[m][k]*B[n][k]   (A=[8192][1024], B=[4096][1024], K contiguous)
// out = C * (0.25 * wscale * act_scale) + bias[n]
#define TILE 128
#define BK   32

__device__ __forceinline__ void async_copy16(const void* g, void* l) {
    __builtin_amdgcn_global_load_lds(
        (const __attribute__((address_space(1))) unsigned int*)g,
        (__attribute__((address_space(3))) unsigned int*)l,
        16, 0, 0);
}

__global__ __launch_bounds__(256, 2) void gemm_kernel(
    const _Float16* __restrict__ A,
    const _Float16* __restrict__ B,
    const float* __restrict__ bias,
    const unsigned int* __restrict__ max_bits,
    const float* __restrict__ wscale,
    float* __restrict__ out) {

    __shared__ alignas(16) _Float16 As[TILE * BK];  // 8 KB, packed [128][32]
    __shared__ alignas(16) _Float16 Bs[TILE * BK];  // 8 KB

    const int t = threadIdx.x;
    const int lane = t & 63;
    const int wave = t >> 6;
    const int wm = (wave >> 1) * 64;   // wave's 64x64 quadrant
    const int wn = (wave & 1) * 64;

    const long rowA0 = (long)blockIdx.y * TILE;
    const long rowB0 = (long)blockIdx.x * TILE;

    f32x4 acc[4][4] = {};

    // staging geometry: chunk c covers tile bytes [c*1024, c*1024+1024)
    // lane's element offset within chunk = lane*8 (16 B); row = c*16 + (lane>>2),
    // col = (lane&3)*8 -> LDS stays packed in exact lane order (global_load_lds req.)
    const int srow = (lane >> 2);
    const int scol = (lane & 3) * 8;

    for (int k0 = 0; k0 < G; k0 += BK) {
        __syncthreads();  // previous iter's ds_reads done before overwrite
        #pragma unroll
        for (int i = 0; i < 2; ++i) {
            const int c = wave + i * 4;                 // chunks 0..7 across 4 waves
            const int row = c * 16 + srow;
            const _Float16* ga = A + (rowA0 + row) * (long)G + k0 + scol;
            const _Float16* gb = B + (rowB0 + row) * (long)G + k0 + scol;
            async_copy16(ga, As + c * 512);
            async_copy16(gb, Bs + c * 512);
        }
        __syncthreads();  // compiler emits s_waitcnt vmcnt(0) before s_barrier

        f16x8 af[4], bf[4];
        #pragma unroll
        for (int mi = 0; mi < 4; ++mi)
            af[mi] = *(const f16x8*)&As[(wm + mi * 16 + (lane & 15)) * BK + (lane >> 4) * 8];
        #pragma unroll
        for (int nj = 0; nj < 4; ++nj)
            bf[nj] = *(const f16x8*)&Bs[(wn + nj * 16 + (lane & 15)) * BK + (lane >> 4) * 8];

        #pragma unroll
        for (int mi = 0; mi < 4; ++mi)
            #pragma unroll
            for (int nj = 0; nj < 4; ++nj)
                acc[mi][nj] = __builtin_amdgcn_mfma_f32_16x16x32_f16(
                    af[mi], bf[nj], acc[mi][nj], 0, 0, 0);
    }

    // epilogue: D[m=(lane>>4)*4+r][n=lane&15]
    const float scale = __uint_as_float(*max_bits) * (0.25f / 127.0f) * wscale[0];
    const int r0 = (int)rowA0 + wm + (lane >> 4) * 4;
    const int c0 = (int)rowB0 + wn + (lane & 15);
    #pragma unroll
    for (int nj = 0; nj < 4; ++nj) {
        const int col = c0 + nj * 16;
        const float b = bias[col];
        #pragma unroll
        for (int mi = 0; mi < 4; ++mi) {
            const int row = r0 + mi * 16;
            #pragma unroll
            for (int r = 0; r < 4; ++r)
                out[(long)(row + r) * OUTF + col] = acc[mi][nj][r] * scale + b;
        }
    }
}

extern "C" void kernel_launch(void* const* d_in, const int* in_sizes, int n_in,
                              void* d_out, int out_size, void* d_ws, size_t ws_size,
                              hipStream_t stream) {
    const float* input  = (const float*)d_in[0];   // [8192][4096]
    const float* weight = (const float*)d_in[1];   // [4096][4096]
    const float* wscale = (const float*)d_in[2];   // [1]
    const float* bias   = (const float*)d_in[3];   // [4096]
    float* out = (float*)d_out;

    unsigned int* max_bits = (unsigned int*)d_ws;
    _Float16* x_sum = (_Float16*)((char*)d_ws + 256);
    _Float16* w_sum = (_Float16*)((char*)d_ws + 256 + (size_t)NROWS * G * 2);

    hipMemsetAsync(d_ws, 0, 4, stream);  // zero absmax accumulator (capture-safe)

    absmax_kernel<<<2048, 256, 0, stream>>>(
        (const float4*)input, NROWS * INF / 4, max_bits);

    quant_kernel<<<(NROWS * G + 255) / 256, 256, 0, stream>>>(
        (const float4*)input, x_sum, max_bits, NROWS * G);

    wsum_kernel<<<(OUTF * G + 255) / 256, 256, 0, stream>>>(
        (const float4*)weight, w_sum, OUTF * G);

    gemm_kernel<<<dim3(OUTF / TILE, NROWS / TILE), 256, 0, stream>>>(
        x_sum, w_sum, bias, max_bits, wscale, out);
}

// Round 2
// 376.146 us; speedup vs baseline: 1.0238x; 1.0238x over previous
//
#include <hip/hip_runtime.h>
#include <hip/hip_bf16.h>

// Problem constants
#define NROWS 8192
#define INF   4096
#define OUTF  4096
#define G     1024          // INF / 4

typedef _Float16 f16x8 __attribute__((ext_vector_type(8)));
typedef float    f32x4 __attribute__((ext_vector_type(4)));

// ws layout:
//   [0]                      float act_scale (= absmax/127)
//   [16 .. 16+4096)          1024 float block-partial maxes
//   [8192 ..)                x_sum fp16 [NROWS][G]   (16 MB)
//   [8192 + NROWS*G*2 ..)    w_sum fp16 [OUTF][G]    (8 MB)

// ---------- Kernel 1a: per-block absmax partials (no global atomics) ----------
__global__ void absmax_part(const float4* __restrict__ x,
                            float* __restrict__ partial) {
    // 8388608 float4 = 1024 blocks * 256 threads * 32 iters exactly
    const int stride = 1024 * 256;
    int i = blockIdx.x * 256 + threadIdx.x;
    float m = 0.f;
    #pragma unroll 4
    for (int it = 0; it < 32; ++it, i += stride) {
        float4 v = x[i];
        m = fmaxf(m, fmaxf(fmaxf(fabsf(v.x), fabsf(v.y)),
                           fmaxf(fabsf(v.z), fabsf(v.w))));
    }
    for (int off = 32; off; off >>= 1)
        m = fmaxf(m, __shfl_down(m, off));
    __shared__ float wm[4];
    int lane = threadIdx.x & 63, wave = threadIdx.x >> 6;
    if (lane == 0) wm[wave] = m;
    __syncthreads();
    if (threadIdx.x == 0)
        partial[blockIdx.x] = fmaxf(fmaxf(wm[0], wm[1]), fmaxf(wm[2], wm[3]));
}

// ---------- Kernel 1b: reduce 1024 partials -> act_scale ----------
__global__ void absmax_final(const float* __restrict__ partial,
                             float* __restrict__ scale_out) {
    int t = threadIdx.x;  // 256 threads
    float m = fmaxf(fmaxf(partial[t], partial[t + 256]),
                    fmaxf(partial[t + 512], partial[t + 768]));
    for (int off = 32; off; off >>= 1)
        m = fmaxf(m, __shfl_down(m, off));
    __shared__ float wm[4];
    int lane = t & 63, wave = t >> 6;
    if (lane == 0) wm[wave] = m;
    __syncthreads();
    if (t == 0) {
        float bm = fmaxf(fmaxf(wm[0], wm[1]), fmaxf(wm[2], wm[3]));
        scale_out[0] = bm * (1.0f / 127.0f);   // act_scale
    }
}

// ---------- Kernel 2: fused quantize+group-sum (x) and group-sum (w) ----------
// blocks [0, 16384): quant path, 2 float4/thread over 8388608 groups
// blocks [16384, 24576): wsum path, 2 float4/thread over 4194304 groups
__global__ void prep_fused(const float4* __restrict__ x,
                           const float4* __restrict__ w,
                           const float* __restrict__ scale_p,
                           _Float16* __restrict__ xs,
                           _Float16* __restrict__ ws) {
    const int b = blockIdx.x;
    const int t = threadIdx.x;
    if (b < 16384) {
        const float s = scale_p[0];
        int i0 = b * 512 + t;
        #pragma unroll
        for (int u = 0; u < 2; ++u) {
            int i = i0 + u * 256;
            float4 v = x[i];
            float q0 = fminf(fmaxf(rintf(v.x / s), -128.f), 127.f);
            float q1 = fminf(fmaxf(rintf(v.y / s), -128.f), 127.f);
            float q2 = fminf(fmaxf(rintf(v.z / s), -128.f), 127.f);
            float q3 = fminf(fmaxf(rintf(v.w / s), -128.f), 127.f);
            xs[i] = (_Float16)(q0 + q1 + q2 + q3);  // integer in [-512,508]: exact
        }
    } else {
        int i0 = (b - 16384) * 512 + t;
        #pragma unroll
        for (int u = 0; u < 2; ++u) {
            int i = i0 + u * 256;
            float4 v = w[i];
            ws[i] = (_Float16)(v.x + v.y + v.z + v.w);  // integer in [-4,4]: exact
        }
    }
}

// ---------- Kernel 3: f16 MFMA GEMM, 256x128 block tile, 128x64 wave tile ----------
// C[m][n] = sum_k A[m][k]*B[n][k]; out = C * (0.25*wscale*act_scale) + bias[n]
#define BM 256
#define BN 128
#define BK 32

__device__ __forceinline__ void async_copy16(const void* g, void* l) {
    __builtin_amdgcn_global_load_lds(
        (const __attribute__((address_space(1))) unsigned int*)g,
        (__attribute__((address_space(3))) unsigned int*)l,
        16, 0, 0);
}

__global__ __launch_bounds__(256, 2) void gemm_kernel(
    const _Float16* __restrict__ A,
    const _Float16* __restrict__ B,
    const float* __restrict__ bias,
    const float* __restrict__ scale_p,
    const float* __restrict__ wscale,
    float* __restrict__ out) {

    __shared__ alignas(16) _Float16 As[BM * BK];  // 16 KB, packed [256][32]
    __shared__ alignas(16) _Float16 Bs[BN * BK];  // 8 KB,  packed [128][32]

    const int t = threadIdx.x;
    const int lane = t & 63;
    const int wave = t >> 6;
    const int wm = (wave >> 1) * 128;   // wave tile: 128 rows x 64 cols
    const int wn = (wave & 1) * 64;

    const long rowA0 = (long)blockIdx.y * BM;
    const long rowB0 = (long)blockIdx.x * BN;

    f32x4 acc[8][4] = {};

    // staging: chunk = 1 KB = 16 rows x 32 f16; lane covers row srow, 8 f16 at scol.
    // 24 chunks (16 A + 8 B) over 4 waves, 6 each; LDS packed in exact lane order.
    const int srow = lane >> 2;
    const int scol = (lane & 3) * 8;

    for (int k0 = 0; k0 < G; k0 += BK) {
        __syncthreads();  // previous iter's ds_reads done before overwrite
        #pragma unroll
        for (int i = 0; i < 6; ++i) {
            const int c = wave * 6 + i;       // wave-uniform chunk id
            if (c < 16) {
                const int row = c * 16 + srow;
                async_copy16(A + (rowA0 + row) * (long)G + k0 + scol, As + c * 512);
            } else {
                const int row = (c - 16) * 16 + srow;
                async_copy16(B + (rowB0 + row) * (long)G + k0 + scol, Bs + (c - 16) * 512);
            }
        }
        __syncthreads();  // compiler drains vmcnt before s_barrier

        f16x8 af[8], bf[4];
        #pragma unroll
        for (int mi = 0; mi < 8; ++mi)
            af[mi] = *(const f16x8*)&As[(wm + mi * 16 + (lane & 15)) * BK + (lane >> 4) * 8];
        #pragma unroll
        for (int nj = 0; nj < 4; ++nj)
            bf[nj] = *(const f16x8*)&Bs[(wn + nj * 16 + (lane & 15)) * BK + (lane >> 4) * 8];

        #pragma unroll
        for (int mi = 0; mi < 8; ++mi)
            #pragma unroll
            for (int nj = 0; nj < 4; ++nj)
                acc[mi][nj] = __builtin_amdgcn_mfma_f32_16x16x32_f16(
                    af[mi], bf[nj], acc[mi][nj], 0, 0, 0);
    }

    // epilogue: D[m=(lane>>4)*4+r][n=lane&15] per 16x16 tile
    const float scale = scale_p[0] * 0.25f * wscale[0];
    const int r0 = (int)rowA0 + wm + (lane >> 4) * 4;
    const int c0 = (int)rowB0 + wn + (lane & 15);
    #pragma unroll
    for (int nj = 0; nj < 4; ++nj) {
        const int col = c0 + nj * 16;
        const float b = bias[col];
        #pragma unroll
        for (int mi = 0; mi < 8; ++mi) {
            const int row = r0 + mi * 16;
            #pragma unroll
            for (int r = 0; r < 4; ++r)
                out[(long)(row + r) * OUTF + col] = acc[mi][nj][r] * scale + b;
        }
    }
}

extern "C" void kernel_launch(void* const* d_in, const int* in_sizes, int n_in,
                              void* d_out, int out_size, void* d_ws, size_t ws_size,
                              hipStream_t stream) {
    const float* input  = (const float*)d_in[0];   // [8192][4096]
    const float* weight = (const float*)d_in[1];   // [4096][4096]
    const float* wscale = (const float*)d_in[2];   // [1]
    const float* bias   = (const float*)d_in[3];   // [4096]
    float* out = (float*)d_out;

    float* act_scale = (float*)d_ws;
    float* partials  = (float*)((char*)d_ws + 16);
    _Float16* x_sum  = (_Float16*)((char*)d_ws + 8192);
    _Float16* w_sum  = (_Float16*)((char*)d_ws + 8192 + (size_t)NROWS * G * 2);

    absmax_part<<<1024, 256, 0, stream>>>((const float4*)input, partials);
    absmax_final<<<1, 256, 0, stream>>>(partials, act_scale);
    prep_fused<<<24576, 256, 0, stream>>>((const float4*)input, (const float4*)weight,
                                          act_scale, x_sum, w_sum);
    gemm_kernel<<<dim3(OUTF / BN, NROWS / BM), 256, 0, stream>>>(
        x_sum, w_sum, bias, act_scale, wscale, out);
}